// Round 2
// baseline (63.198 us; speedup 1.0000x reference)
//
#include <hip/hip_runtime.h>
#include <math.h>

#define NB 1024
#define IC 3
#define HW 32
#define GCH 16
#define ECH 32
#define NE 8
#define NC 100

// ---------------- kernel 1: gate conv + pool + linear + softmax + argmax ----
__global__ __launch_bounds__(256) void gate_kernel(
    const float* __restrict__ x,     // [1024,3,32,32]
    const float* __restrict__ gcw,   // [16,3,3,3]
    const float* __restrict__ gcb,   // [16]
    const float* __restrict__ glw,   // [8,16]
    const float* __restrict__ glb,   // [8]
    float* __restrict__ out_w,       // [1024,8]
    int* __restrict__ best)          // [1024]
{
    __shared__ float xs[IC][34][34];
    __shared__ float red[4 * GCH];
    __shared__ float pg[GCH];
    __shared__ float sm[NE];

    const int t = threadIdx.x;
    const int b = blockIdx.x;
    const int lane = t & 63;
    const int wid = t >> 6;

    // zero-pad + vectorized load of x[b] into LDS
    for (int i = t; i < IC * 34 * 34; i += 256) ((float*)xs)[i] = 0.f;
    __syncthreads();
    const float* xb = x + (size_t)b * (IC * HW * HW);
    for (int f = t; f < (IC * HW * HW) / 4; f += 256) {
        float4 v = ((const float4*)xb)[f];
        int e4 = f << 2;
        int ci = e4 >> 10, r = e4 & 1023, y = r >> 5, xx = r & 31;
        float* dst = &xs[ci][y + 1][xx + 1];
        dst[0] = v.x; dst[1] = v.y; dst[2] = v.z; dst[3] = v.w;
    }
    __syncthreads();

    // per-thread patch: 4 consecutive pixels in one row
    const int py = t >> 3;
    const int px0 = (t & 7) << 2;
    float xr[IC][3][6];
    #pragma unroll
    for (int ci = 0; ci < IC; ++ci)
        #pragma unroll
        for (int ky = 0; ky < 3; ++ky)
            #pragma unroll
            for (int cc = 0; cc < 6; ++cc)
                xr[ci][ky][cc] = xs[ci][py + ky][px0 + cc];

    float gsum[GCH];
    #pragma unroll 2
    for (int c = 0; c < GCH; ++c) {
        const float* w = gcw + c * 27;
        float wv[27];
        #pragma unroll
        for (int k = 0; k < 27; ++k) wv[k] = w[k];
        float p0 = 0.f, p1 = 0.f, p2 = 0.f, p3 = 0.f;
        #pragma unroll
        for (int ci = 0; ci < IC; ++ci)
            #pragma unroll
            for (int ky = 0; ky < 3; ++ky)
                #pragma unroll
                for (int kx = 0; kx < 3; ++kx) {
                    float wvv = wv[(ci * 3 + ky) * 3 + kx];
                    p0 += xr[ci][ky][kx + 0] * wvv;
                    p1 += xr[ci][ky][kx + 1] * wvv;
                    p2 += xr[ci][ky][kx + 2] * wvv;
                    p3 += xr[ci][ky][kx + 3] * wvv;
                }
        float bias = gcb[c];
        gsum[c] = fmaxf(p0 + bias, 0.f) + fmaxf(p1 + bias, 0.f) +
                  fmaxf(p2 + bias, 0.f) + fmaxf(p3 + bias, 0.f);
    }

    #pragma unroll
    for (int c = 0; c < GCH; ++c) {
        float v = gsum[c];
        #pragma unroll
        for (int off = 1; off < 64; off <<= 1) v += __shfl_xor(v, off);
        if (lane == 0) red[wid * GCH + c] = v;
    }
    __syncthreads();
    if (t < GCH) {
        pg[t] = (red[t] + red[GCH + t] + red[2 * GCH + t] + red[3 * GCH + t])
                * (1.f / 1024.f);
    }
    __syncthreads();

    if (t < NE) {
        float acc = glb[t];
        #pragma unroll
        for (int c = 0; c < GCH; ++c) acc += pg[c] * glw[t * GCH + c];
        sm[t] = acc;
    }
    __syncthreads();

    if (t == 0) {
        float m = sm[0]; int bi = 0;
        for (int e2 = 1; e2 < NE; ++e2)
            if (sm[e2] > m) { m = sm[e2]; bi = e2; }
        float wexp[NE]; float ssum = 0.f;
        for (int e2 = 0; e2 < NE; ++e2) { wexp[e2] = expf(sm[e2] - m); ssum += wexp[e2]; }
        float inv = 1.f / ssum;
        for (int e2 = 0; e2 < NE; ++e2) out_w[(size_t)b * NE + e2] = wexp[e2] * inv;
        best[b] = bi;
    }
}

// ---------------- kernel 2: selected expert conv + pool + linear ------------
__global__ __launch_bounds__(256) void expert_kernel(
    const float* __restrict__ x,     // [1024,3,32,32]
    const float* __restrict__ ecw,   // [8,32,3,3,3]
    const float* __restrict__ ecb,   // [8,32]
    const float* __restrict__ elw,   // [8,100,32]
    const float* __restrict__ elb,   // [8,100]
    const int* __restrict__ best,    // [1024]
    float* __restrict__ out_final)   // [1024,100]
{
    __shared__ float xs[IC][34][34];
    __shared__ float red[4 * ECH];
    __shared__ float pe[ECH];

    const int t = threadIdx.x;
    const int b = blockIdx.x;
    const int lane = t & 63;
    const int wid = t >> 6;

    const int e = best[b];   // uniform per block

    for (int i = t; i < IC * 34 * 34; i += 256) ((float*)xs)[i] = 0.f;
    __syncthreads();
    const float* xb = x + (size_t)b * (IC * HW * HW);
    for (int f = t; f < (IC * HW * HW) / 4; f += 256) {
        float4 v = ((const float4*)xb)[f];
        int e4 = f << 2;
        int ci = e4 >> 10, r = e4 & 1023, y = r >> 5, xx = r & 31;
        float* dst = &xs[ci][y + 1][xx + 1];
        dst[0] = v.x; dst[1] = v.y; dst[2] = v.z; dst[3] = v.w;
    }
    __syncthreads();

    const int py = t >> 3;
    const int px0 = (t & 7) << 2;
    float xr[IC][3][6];
    #pragma unroll
    for (int ci = 0; ci < IC; ++ci)
        #pragma unroll
        for (int ky = 0; ky < 3; ++ky)
            #pragma unroll
            for (int cc = 0; cc < 6; ++cc)
                xr[ci][ky][cc] = xs[ci][py + ky][px0 + cc];

    float esum[ECH];
    const float* ewp = ecw + (size_t)e * (ECH * 27);
    const float* ebp = ecb + (size_t)e * ECH;
    #pragma unroll 2
    for (int c = 0; c < ECH; ++c) {
        const float* w = ewp + c * 27;
        float wv[27];
        #pragma unroll
        for (int k = 0; k < 27; ++k) wv[k] = w[k];
        float p0 = 0.f, p1 = 0.f, p2 = 0.f, p3 = 0.f;
        #pragma unroll
        for (int ci = 0; ci < IC; ++ci)
            #pragma unroll
            for (int ky = 0; ky < 3; ++ky)
                #pragma unroll
                for (int kx = 0; kx < 3; ++kx) {
                    float wvv = wv[(ci * 3 + ky) * 3 + kx];
                    p0 += xr[ci][ky][kx + 0] * wvv;
                    p1 += xr[ci][ky][kx + 1] * wvv;
                    p2 += xr[ci][ky][kx + 2] * wvv;
                    p3 += xr[ci][ky][kx + 3] * wvv;
                }
        float bias = ebp[c];
        esum[c] = fmaxf(p0 + bias, 0.f) + fmaxf(p1 + bias, 0.f) +
                  fmaxf(p2 + bias, 0.f) + fmaxf(p3 + bias, 0.f);
    }

    #pragma unroll
    for (int c = 0; c < ECH; ++c) {
        float v = esum[c];
        #pragma unroll
        for (int off = 1; off < 64; off <<= 1) v += __shfl_xor(v, off);
        if (lane == 0) red[wid * ECH + c] = v;
    }
    __syncthreads();
    if (t < ECH) {
        pe[t] = (red[t] + red[ECH + t] + red[2 * ECH + t] + red[3 * ECH + t])
                * (1.f / 1024.f);
    }
    __syncthreads();

    if (t < NC) {
        const float* lw = elw + ((size_t)e * NC + t) * ECH;
        float acc = elb[e * NC + t];
        #pragma unroll
        for (int c = 0; c < ECH; ++c) acc += pe[c] * lw[c];
        out_final[(size_t)b * NC + t] = acc;
    }
}

extern "C" void kernel_launch(void* const* d_in, const int* in_sizes, int n_in,
                              void* d_out, int out_size, void* d_ws, size_t ws_size,
                              hipStream_t stream) {
    const float* x   = (const float*)d_in[0];
    const float* gcw = (const float*)d_in[1];
    const float* gcb = (const float*)d_in[2];
    const float* glw = (const float*)d_in[3];
    const float* glb = (const float*)d_in[4];
    const float* ecw = (const float*)d_in[5];
    const float* ecb = (const float*)d_in[6];
    const float* elw = (const float*)d_in[7];
    const float* elb = (const float*)d_in[8];

    float* out_final = (float*)d_out;             // [1024,100]
    float* out_w     = (float*)d_out + NB * NC;   // [1024,8]
    int*   best      = (int*)d_ws;                // [1024]

    hipLaunchKernelGGL(gate_kernel, dim3(NB), dim3(256), 0, stream,
                       x, gcw, gcb, glw, glb, out_w, best);
    hipLaunchKernelGGL(expert_kernel, dim3(NB), dim3(256), 0, stream,
                       x, ecw, ecb, elw, elb, best, out_final);
}

// Round 3
// 53.883 us; speedup vs baseline: 1.1729x; 1.1729x over previous
//
#include <hip/hip_runtime.h>
#include <math.h>

#define NB 1024
#define IC 3
#define HW 32
#define GCH 16
#define ECH 32
#define NE 8
#define NC 100

// One block per sample. __launch_bounds__(256,4): 4 waves/EU (=16 waves/CU,
// matching the 4-blocks/CU grid ceiling) -> VGPR cap 128, so the 54-float
// input patch stays register-resident instead of being re-read from LDS.
__global__ __launch_bounds__(256, 4) void moe_fused_kernel(
    const float* __restrict__ x,     // [1024,3,32,32]
    const float* __restrict__ gcw,   // [16,3,3,3]
    const float* __restrict__ gcb,   // [16]
    const float* __restrict__ glw,   // [8,16]
    const float* __restrict__ glb,   // [8]
    const float* __restrict__ ecw,   // [8,32,3,3,3]
    const float* __restrict__ ecb,   // [8,32]
    const float* __restrict__ elw,   // [8,100,32]
    const float* __restrict__ elb,   // [8,100]
    float* __restrict__ out_final,   // [1024,100]
    float* __restrict__ out_w)       // [1024,8]
{
    __shared__ float xs[IC][34][34];
    __shared__ float red[4][ECH];
    __shared__ float pg[GCH];
    __shared__ float pe[ECH];
    __shared__ int s_best;

    const int t = threadIdx.x;
    const int b = blockIdx.x;
    const int lane = t & 63;
    const int wid = t >> 6;

    // ---- zero-pad + vectorized load of x[b] into LDS ----
    for (int i = t; i < IC * 34 * 34; i += 256) ((float*)xs)[i] = 0.f;
    __syncthreads();
    const float* xb = x + (size_t)b * (IC * HW * HW);
    for (int f = t; f < (IC * HW * HW) / 4; f += 256) {
        float4 v = ((const float4*)xb)[f];
        int e4 = f << 2;
        int ci = e4 >> 10, r = e4 & 1023, y = r >> 5, xx = r & 31;
        float* dst = &xs[ci][y + 1][xx + 1];
        dst[0] = v.x; dst[1] = v.y; dst[2] = v.z; dst[3] = v.w;
    }
    __syncthreads();

    // ---- per-thread patch: 4 consecutive pixels of one output row ----
    const int py = t >> 3;          // 0..31
    const int px0 = (t & 7) << 2;   // 0..28
    float xr[IC][3][6];
    #pragma unroll
    for (int ci = 0; ci < IC; ++ci)
        #pragma unroll
        for (int ky = 0; ky < 3; ++ky)
            #pragma unroll
            for (int cc = 0; cc < 6; ++cc)
                xr[ci][ky][cc] = xs[ci][py + ky][px0 + cc];

    // ---- gate conv + relu + immediate per-channel pool reduce ----
    #pragma unroll 2
    for (int c = 0; c < GCH; ++c) {
        const float* w = gcw + c * 27;   // uniform -> s_load -> SGPR operands
        float p0 = 0.f, p1 = 0.f, p2 = 0.f, p3 = 0.f;
        #pragma unroll
        for (int ci = 0; ci < IC; ++ci)
            #pragma unroll
            for (int ky = 0; ky < 3; ++ky)
                #pragma unroll
                for (int kx = 0; kx < 3; ++kx) {
                    float wv = w[(ci * 3 + ky) * 3 + kx];
                    p0 += xr[ci][ky][kx + 0] * wv;
                    p1 += xr[ci][ky][kx + 1] * wv;
                    p2 += xr[ci][ky][kx + 2] * wv;
                    p3 += xr[ci][ky][kx + 3] * wv;
                }
        float bias = gcb[c];
        float v = fmaxf(p0 + bias, 0.f) + fmaxf(p1 + bias, 0.f) +
                  fmaxf(p2 + bias, 0.f) + fmaxf(p3 + bias, 0.f);
        #pragma unroll
        for (int off = 1; off < 64; off <<= 1) v += __shfl_xor(v, off);
        if (lane == 0) red[wid][c] = v;
    }
    __syncthreads();
    if (t < GCH)
        pg[t] = (red[0][t] + red[1][t] + red[2][t] + red[3][t]) * (1.f / 1024.f);
    __syncthreads();

    // ---- gate linear + softmax + argmax, lanes 0..7 of wave 0 ----
    if (t < NE) {
        float acc = glb[t];
        #pragma unroll
        for (int c = 0; c < GCH; ++c) acc += pg[c] * glw[t * GCH + c];
        // max over 8 lanes
        float m = acc;
        #pragma unroll
        for (int off = 1; off < NE; off <<= 1) m = fmaxf(m, __shfl_xor(m, off));
        float ex = expf(acc - m);
        float s = ex;
        #pragma unroll
        for (int off = 1; off < NE; off <<= 1) s += __shfl_xor(s, off);
        out_w[(size_t)b * NE + t] = ex / s;
        // argmax (first index on ties, matching jnp.argmax)
        float mv = acc; int mi = t;
        #pragma unroll
        for (int off = 1; off < NE; off <<= 1) {
            float ov = __shfl_xor(mv, off);
            int   oi = __shfl_xor(mi, off);
            if (ov > mv || (ov == mv && oi < mi)) { mv = ov; mi = oi; }
        }
        if (t == 0) s_best = mi;
    }
    __syncthreads();
    const int e = __builtin_amdgcn_readfirstlane(s_best);

    // ---- selected expert conv + relu + immediate per-channel pool reduce ----
    const float* ewp = ecw + (size_t)e * (ECH * 27);
    const float* ebp = ecb + (size_t)e * ECH;
    #pragma unroll 2
    for (int c = 0; c < ECH; ++c) {
        const float* w = ewp + c * 27;   // uniform -> s_load
        float p0 = 0.f, p1 = 0.f, p2 = 0.f, p3 = 0.f;
        #pragma unroll
        for (int ci = 0; ci < IC; ++ci)
            #pragma unroll
            for (int ky = 0; ky < 3; ++ky)
                #pragma unroll
                for (int kx = 0; kx < 3; ++kx) {
                    float wv = w[(ci * 3 + ky) * 3 + kx];
                    p0 += xr[ci][ky][kx + 0] * wv;
                    p1 += xr[ci][ky][kx + 1] * wv;
                    p2 += xr[ci][ky][kx + 2] * wv;
                    p3 += xr[ci][ky][kx + 3] * wv;
                }
        float bias = ebp[c];
        float v = fmaxf(p0 + bias, 0.f) + fmaxf(p1 + bias, 0.f) +
                  fmaxf(p2 + bias, 0.f) + fmaxf(p3 + bias, 0.f);
        #pragma unroll
        for (int off = 1; off < 64; off <<= 1) v += __shfl_xor(v, off);
        if (lane == 0) red[wid][c] = v;
    }
    __syncthreads();
    if (t < ECH)
        pe[t] = (red[0][t] + red[1][t] + red[2][t] + red[3][t]) * (1.f / 1024.f);
    __syncthreads();

    // ---- expert linear: 100 outputs ----
    if (t < NC) {
        const float* lw = elw + ((size_t)e * NC + t) * ECH;
        float acc = elb[e * NC + t];
        #pragma unroll
        for (int c = 0; c < ECH; ++c) acc += pe[c] * lw[c];
        out_final[(size_t)b * NC + t] = acc;
    }
}

extern "C" void kernel_launch(void* const* d_in, const int* in_sizes, int n_in,
                              void* d_out, int out_size, void* d_ws, size_t ws_size,
                              hipStream_t stream) {
    const float* x   = (const float*)d_in[0];
    const float* gcw = (const float*)d_in[1];
    const float* gcb = (const float*)d_in[2];
    const float* glw = (const float*)d_in[3];
    const float* glb = (const float*)d_in[4];
    const float* ecw = (const float*)d_in[5];
    const float* ecb = (const float*)d_in[6];
    const float* elw = (const float*)d_in[7];
    const float* elb = (const float*)d_in[8];

    float* out_final = (float*)d_out;             // [1024,100]
    float* out_w     = (float*)d_out + NB * NC;   // [1024,8]

    hipLaunchKernelGGL(moe_fused_kernel, dim3(NB), dim3(256), 0, stream,
                       x, gcw, gcb, glw, glb, ecw, ecb, elw, elb,
                       out_final, out_w);
}